// Round 9
// baseline (190.876 us; speedup 1.0000x reference)
//
#include <hip/hip_runtime.h>

#define NB 4
#define NT 40000
#define NS0 30000
#define ND0 15000
#define NE0 360000
#define ND1 7500
#define NE1 180000
#define NEG 0.2f

#define CAP 64                            // bucket capacity per dst (avg deg 24)
#define GEMB 938                          // gemm blocks (2 x 64-row tiles each)
#define SBI  264                          // scatter blocks (8 edges/thread)
// grid = SBI*4 (interleaved region) + (GEMB - SBI*3) = 1202

// transposed bucket slot: logical pos p -> physical (p&7)*8 + (p>>3).
// Lane-group grp's 4 edges for iteration k (logical grp+32k+{0,8,16,24})
// land at physical grp*8 + 4k + {0,1,2,3}  -> ONE int4 load per iteration.
#define BKT(p) ((((p) & 7) << 3) | ((p) >> 3))

typedef __attribute__((ext_vector_type(8))) short bf8;
typedef __attribute__((ext_vector_type(4))) float f4;
typedef __attribute__((ext_vector_type(2))) float f2;

__device__ __forceinline__ unsigned short f2bf(float f) {
    unsigned u = __float_as_uint(f);
    u += 0x7FFF + ((u >> 16) & 1);          // round-to-nearest-even
    return (unsigned short)(u >> 16);
}
// unpack a packed bf16 pair (one uint) to 2 floats -> feeds v_pk_fma_f32
__device__ __forceinline__ f2 upk(unsigned u) {
    f2 r;
    r.x = __uint_as_float(u << 16);
    r.y = __uint_as_float(u & 0xFFFF0000u);
    return r;
}

// -------- fused: layer-1 MFMA GEMM + bucket scatter (CSR without scan) -----
// Scatter blocks INTERLEAVED 1-in-4 with GEMM blocks: atomic-latency-bound
// scatter waves co-reside with gather/LDS-bound GEMM waves (disjoint pipes)
// instead of running as a thin tail. GEMM blocks process 2 x 64-row tiles,
// staging W1 once per 128 rows (half the staging + block-launch overhead).
__global__ __launch_bounds__(256) void kA_gemm_scat(
        const float* __restrict__ x, const int* __restrict__ n_id0,
        const float* __restrict__ W1, const float* __restrict__ a_src,
        const float* __restrict__ a_dst,
        unsigned short* __restrict__ ht1b, float* __restrict__ es1, float* __restrict__ ed1,
        const int* __restrict__ esrc0, const int* __restrict__ edst0,
        const int* __restrict__ esrc1, const int* __restrict__ edst1,
        int* __restrict__ cur0, int* __restrict__ cur1,
        int* __restrict__ srcsort0, int* __restrict__ srcsort1) {
    __shared__ unsigned short xtb[64*72];
    __shared__ unsigned short wtb[64*72];
    __shared__ float asl[64], adl[64];
    int bid = blockIdx.x;
    int sid = -1, gid = 0;
    if (bid < SBI*4) {                     // interleaved region: 1 scatter per 4
        if ((bid & 3) == 0) sid = bid >> 2;
        else gid = (bid >> 2) * 3 + (bid & 3) - 1;    // 0..791
    } else {
        gid = bid - SBI;                   // 792..937
    }
    if (sid >= 0) {                        // ---- scatter part ----
        int base = sid * 2048 + threadIdx.x;
        #pragma unroll
        for (int p = 0; p < 8; ++p) {
            int t = base + p * 256;
            if (t < NE0) {
                int d = edst0[t];
                int pos = atomicAdd(&cur0[d], 1);
                if (pos < CAP) srcsort0[d*CAP + BKT(pos)] = esrc0[t];
            } else if (t < NE0 + NE1) {
                int e = t - NE0;
                int d = edst1[e];
                int pos = atomicAdd(&cur1[d], 1);
                if (pos < CAP) srcsort1[d*CAP + BKT(pos)] = esrc1[e];
            }
        }
        return;
    }
    // ---- GEMM part: W1 staged once, two 64-row tiles ----
    int t = threadIdx.x;
    {
        int k = t >> 2, nb = (t & 3) * 16;
        const float* wrow = &W1[k*64 + nb];
        #pragma unroll
        for (int j = 0; j < 16; j += 4) {
            float4 v = *(const float4*)&wrow[j];
            wtb[(nb+j+0)*72 + k] = f2bf(v.x);
            wtb[(nb+j+1)*72 + k] = f2bf(v.y);
            wtb[(nb+j+2)*72 + k] = f2bf(v.z);
            wtb[(nb+j+3)*72 + k] = f2bf(v.w);
        }
    }
    if (t < 64) { asl[t] = a_src[t]; adl[t] = a_dst[t]; }
    for (int tile = 0; tile < 2; ++tile) {
        int rowbase = gid * 128 + tile * 64;
        {
            // Cooperative gather: 4 consecutive lanes share one row (16
            // lines per instruction instead of 64). OOB rows (last block's
            // 2nd tile) clamp to row 0; their stores are guarded below.
            int r   = t >> 2;
            int sub = t & 3;
            int row_s = rowbase + r;
            int rs = row_s < NB*NS0 ? row_s : 0;
            int bs = rs / NS0;
            int ns = rs - bs * NS0;
            const float* xrow = x + ((size_t)(bs * NT + n_id0[ns])) * 64;
            #pragma unroll
            for (int j = 0; j < 4; ++j) {
                int kf = (sub + j*4) * 4;
                float4 v = *(const float4*)&xrow[kf];
                ushort4 u;
                u.x = f2bf(v.x); u.y = f2bf(v.y); u.z = f2bf(v.z); u.w = f2bf(v.w);
                *(ushort4*)&xtb[r*72 + kf] = u;
            }
        }
        __syncthreads();
        int w = t >> 6, lane = t & 63, quad = lane >> 4, cl = lane & 15;
        int arow = 16*w + cl;
        bf8 a0 = *(const bf8*)&xtb[arow*72 + quad*8];        // A[m=cl][k=quad*8+j]
        bf8 a1 = *(const bf8*)&xtb[arow*72 + 32 + quad*8];   // k+32
        f4 acc[4];
        #pragma unroll
        for (int sub = 0; sub < 4; ++sub) {
            int n = sub*16 + cl;
            bf8 b0 = *(const bf8*)&wtb[n*72 + quad*8];       // B[k][n=cl]
            bf8 b1v = *(const bf8*)&wtb[n*72 + 32 + quad*8];
            f4 c = {0.f, 0.f, 0.f, 0.f};
            c = __builtin_amdgcn_mfma_f32_16x16x32_bf16(a0, b0, c, 0, 0, 0);
            c = __builtin_amdgcn_mfma_f32_16x16x32_bf16(a1, b1v, c, 0, 0, 0);
            acc[sub] = c;
        }
        // ---- LDS bounce: C-tile -> xtb (reuse) -> coalesced global ----
        __syncthreads();                   // all xtb/wtb fragment reads done
        unsigned short* ob = xtb;          // 64 rows x 64 ushort (8 KB)
        #pragma unroll
        for (int sub = 0; sub < 4; ++sub)
            #pragma unroll
            for (int r = 0; r < 4; ++r)
                ob[(16*w + 4*quad + r)*64 + sub*16 + cl] = f2bf(acc[sub][r]);
        // es/ed epilogue (registers + scalar stores, row-guarded)
        int rbase = rowbase + 16*w + quad*4;
        #pragma unroll
        for (int r = 0; r < 4; ++r) {
            #pragma unroll
            for (int sub = 0; sub < 4; ++sub) {
                int col = sub*16 + cl;
                float ps = acc[sub][r] * asl[col];
                float pd = acc[sub][r] * adl[col];
                ps += __shfl_xor(ps, 1); ps += __shfl_xor(ps, 2); ps += __shfl_xor(ps, 4);
                pd += __shfl_xor(pd, 1); pd += __shfl_xor(pd, 2); pd += __shfl_xor(pd, 4);
                if ((cl & 7) == 0 && rbase + r < NB*NS0) {
                    int h = sub*2 + (cl >> 3);
                    es1[(rbase + r)*8 + h] = ps;
                    ed1[(rbase + r)*8 + h] = pd;
                }
            }
        }
        __syncthreads();                   // ob fully written
        {
            int row = t >> 3;              // 0..31
            int c8  = t & 7;               // 16-B chunk -> superbank = c8
            #pragma unroll
            for (int rep = 0; rep < 2; ++rep) {
                int rr2 = row + rep*32;
                int grow = rowbase + rr2;
                if (grow < NB*NS0) {
                    uint4 v = *(const uint4*)&ob[rr2*64 + c8*8];
                    *(uint4*)&ht1b[(size_t)grow*64 + c8*8] = v;   // 1024 B/wave-inst
                }
            }
        }
        __syncthreads();                   // ob reads done before next gather
    }
}

// -------- fused: layer-1 aggregation + layer-2 node transform --------------
// (unchanged from R7: 256-thread, 4 dst/block, XCD-pinned, int4 bucket loads,
// pk_fma accumulation, DS-lean epilogue)
__global__ __launch_bounds__(256) void k3_agg1_node2(
        const int* __restrict__ srcsort0, const int* __restrict__ cur0,
        const int* __restrict__ res0,
        const float* __restrict__ es1, const float* __restrict__ ed1,
        const unsigned short* __restrict__ ht1b, const float* __restrict__ b1,
        const float* __restrict__ W2, const float* __restrict__ a_src2,
        const float* __restrict__ a_dst2,
        float* __restrict__ ht2, float* __restrict__ es2, float* __restrict__ ed2) {
    __shared__ float W2t[32][68];          // W2t[c2][k] = W2[k][c2]
    __shared__ float as2[32], ad2[32];
    __shared__ float b1l[64];
    __shared__ float hsh[4][64];           // per-wave h(d)
    int t = threadIdx.x;
    {   // coalesced W2 read (8 KB) + transposed LDS write
        float4 v0 = *(const float4*)&W2[t*8];
        float4 v1 = *(const float4*)&W2[t*8 + 4];
        int k = t >> 2, c = (t & 3) * 8;
        W2t[c+0][k] = v0.x; W2t[c+1][k] = v0.y; W2t[c+2][k] = v0.z; W2t[c+3][k] = v0.w;
        W2t[c+4][k] = v1.x; W2t[c+5][k] = v1.y; W2t[c+6][k] = v1.z; W2t[c+7][k] = v1.w;
    }
    if (t < 32) { as2[t] = a_src2[t]; ad2[t] = a_dst2[t]; }
    if (t < 64) b1l[t] = b1[t];
    __syncthreads();                       // only barrier in the kernel
    int xcd = blockIdx.x & 7;
    int b = xcd >> 1;                      // batch pinned to XCD pair
    int chunk = (blockIdx.x >> 3) * 2 + (xcd & 1);   // 0..3749 (bijective)
    int wv = t >> 6;
    int d = chunk * 4 + wv;
    int lane = t & 63;
    int grp = lane >> 3;                   // edge slot 0..7
    int c = lane & 7;                      // head index; channels 8c..8c+7
    int dn = res0[d];
    float edv = ed1[(b*NS0 + dn)*8 + c];
    int start = d * CAP;
    int cnt = min(cur0[d], CAP);
    const float* esb = es1 + (size_t)b*NS0*8;
    const unsigned short* htb = ht1b + (size_t)b*NS0*64;
    f2 a01 = {0.f, 0.f}, a23 = {0.f, 0.f}, a45 = {0.f, 0.f}, a67 = {0.f, 0.f};
    float wsum = 0.f;
    int i = grp;
    int pp = start + grp*8;                // physical int4 slot for iteration 0
    int4 sv = *(const int4*)&srcsort0[pp];
    bool v0 = i      < cnt, v1 = i + 8  < cnt,
         v2 = i + 16 < cnt, v3 = i + 24 < cnt;
    int s0 = v0 ? sv.x : 0;
    int s1 = v1 ? sv.y : 0;
    int s2 = v2 ? sv.z : 0;
    int s3 = v3 ? sv.w : 0;
    for (;;) {
        float e0 = esb[s0*8 + c], e1 = esb[s1*8 + c];
        float e2 = esb[s2*8 + c], e3 = esb[s3*8 + c];
        uint4 h0 = *(const uint4*)&htb[(size_t)s0*64 + c*8];
        uint4 h1 = *(const uint4*)&htb[(size_t)s1*64 + c*8];
        uint4 h2 = *(const uint4*)&htb[(size_t)s2*64 + c*8];
        uint4 h3 = *(const uint4*)&htb[(size_t)s3*64 + c*8];
        int ni = i + 32;
        bool nv0 = false, nv1 = false, nv2 = false, nv3 = false;
        int t0 = 0, t1 = 0, t2 = 0, t3 = 0;
        if (ni < cnt) {                    // wave-uniform: skip prefetch on final iter
            int4 nsv = *(const int4*)&srcsort0[pp + 4];
            nv0 = true;            nv1 = ni + 8  < cnt;
            nv2 = ni + 16 < cnt;   nv3 = ni + 24 < cnt;
            t0 =       nsv.x;
            t1 = nv1 ? nsv.y : 0;
            t2 = nv2 ? nsv.z : 0;
            t3 = nv3 ? nsv.w : 0;
        }
        e0 += edv; e1 += edv; e2 += edv; e3 += edv;
        e0 = e0 > 0.f ? e0 : NEG * e0;
        e1 = e1 > 0.f ? e1 : NEG * e1;
        e2 = e2 > 0.f ? e2 : NEG * e2;
        e3 = e3 > 0.f ? e3 : NEG * e3;
        float w0 = v0 ? __expf(e0) : 0.f;
        float w1 = v1 ? __expf(e1) : 0.f;
        float w2 = v2 ? __expf(e2) : 0.f;
        float w3 = v3 ? __expf(e3) : 0.f;
        a01 += w0 * upk(h0.x); a23 += w0 * upk(h0.y);
        a45 += w0 * upk(h0.z); a67 += w0 * upk(h0.w);
        a01 += w1 * upk(h1.x); a23 += w1 * upk(h1.y);
        a45 += w1 * upk(h1.z); a67 += w1 * upk(h1.w);
        a01 += w2 * upk(h2.x); a23 += w2 * upk(h2.y);
        a45 += w2 * upk(h2.z); a67 += w2 * upk(h2.w);
        a01 += w3 * upk(h3.x); a23 += w3 * upk(h3.y);
        a45 += w3 * upk(h3.z); a67 += w3 * upk(h3.w);
        wsum += (w0 + w1) + (w2 + w3);
        i = ni; pp += 4;
        s0 = t0; s1 = t1; s2 = t2; s3 = t3;
        v0 = nv0; v1 = nv1; v2 = nv2; v3 = nv3;
        if (i >= cnt) break;
    }
    float acc[8] = {a01.x, a01.y, a23.x, a23.y, a45.x, a45.y, a67.x, a67.y};
    // ---- butterfly reduce-scatter over the 8 edge-slot groups ----
    int g0 = grp & 1, g1 = (grp >> 1) & 1, g2 = grp >> 2;
    float n0, n1, n2, n3;
    {
        float s, r;
        s = g0 ? acc[0] : acc[1]; r = __shfl_xor(s, 8);  n0 = (g0 ? acc[1] : acc[0]) + r;
        s = g0 ? acc[2] : acc[3]; r = __shfl_xor(s, 8);  n1 = (g0 ? acc[3] : acc[2]) + r;
        s = g0 ? acc[4] : acc[5]; r = __shfl_xor(s, 8);  n2 = (g0 ? acc[5] : acc[4]) + r;
        s = g0 ? acc[6] : acc[7]; r = __shfl_xor(s, 8);  n3 = (g0 ? acc[7] : acc[6]) + r;
    }
    float m0, m1;
    {
        float s, r;
        s = g1 ? n0 : n1; r = __shfl_xor(s, 16); m0 = (g1 ? n1 : n0) + r;
        s = g1 ? n2 : n3; r = __shfl_xor(s, 16); m1 = (g1 ? n3 : n2) + r;
    }
    float fin;
    {
        float s = g2 ? m0 : m1; float r = __shfl_xor(s, 32); fin = (g2 ? m1 : m0) + r;
    }
    wsum += __shfl_xor(wsum, 8); wsum += __shfl_xor(wsum, 16); wsum += __shfl_xor(wsum, 32);
    float inv = cnt > 0 ? 1.f / wsum : 0.f;
    float o = fin * inv + b1l[(c << 3) | grp];
    o = o > 0.f ? o : __expf(o) - 1.f;     // ELU: 1 exp/lane, all 64 lanes
    hsh[wv][(c << 3) | grp] = o;
    // hsh[wv] written+read by the SAME wave -> lgkmcnt ordering suffices.
    // ---- layer-2 node transform: out[c2] = sum_k h[k] * W2t[c2][k] ----
    int c2 = lane & 31, half = lane >> 5;
    const float4* hp = (const float4*)&hsh[wv][half * 32];
    const float4* wp = (const float4*)&W2t[c2][half * 32];
    float acc2 = 0.f;
    #pragma unroll
    for (int q = 0; q < 8; ++q) {
        float4 hv = hp[q];
        float4 w4 = wp[q];
        acc2 = fmaf(hv.x, w4.x, acc2); acc2 = fmaf(hv.y, w4.y, acc2);
        acc2 = fmaf(hv.z, w4.z, acc2); acc2 = fmaf(hv.w, w4.w, acc2);
    }
    acc2 += __shfl_xor(acc2, 32);
    float ps = acc2 * as2[c2];
    float pd = acc2 * ad2[c2];
    ps += __shfl_xor(ps, 1); ps += __shfl_xor(ps, 2); ps += __shfl_xor(ps, 4);
    ps += __shfl_xor(ps, 8); ps += __shfl_xor(ps, 16);
    pd += __shfl_xor(pd, 1); pd += __shfl_xor(pd, 2); pd += __shfl_xor(pd, 4);
    pd += __shfl_xor(pd, 8); pd += __shfl_xor(pd, 16);
    int row = b*ND0 + d;
    if (half == 0) ht2[(size_t)row*32 + c2] = acc2;   // coalesced 128 B
    if (lane == 0) { es2[row] = ps; ed2[row] = pd; }
}

// ---------------- layer 2 per-dst aggregation ------------------------------
// (unchanged from R7: 256-thread, pinned, grid 7504 + guard, int4 loads)
__global__ __launch_bounds__(256) void k7_agg2(
        const int* __restrict__ srcsort1, const int* __restrict__ cur1,
        const int* __restrict__ res1,
        const float* __restrict__ es2, const float* __restrict__ ed2,
        const float* __restrict__ ht2, const float* __restrict__ b2,
        float* __restrict__ outp) {
    int xcd = blockIdx.x & 7;
    int b = xcd >> 1;
    int chunk = (blockIdx.x >> 3) * 2 + (xcd & 1);
    if (chunk >= ND1/4) return;            // pad blocks (grid 7504)
    int d = chunk * 4 + (threadIdx.x >> 6);
    int lane = threadIdx.x & 63;
    int grp = lane >> 3;                   // edge slot 0..7
    int c = lane & 7;                      // channel quad: channels 4c..4c+3
    int dn = res1[d];
    float edv = ed2[b*ND0 + dn];
    int start = d * CAP;
    int cnt = min(cur1[d], CAP);
    const float* esb = es2 + (size_t)b*ND0;
    const float* htb = ht2 + (size_t)b*ND0*32;
    f4 accv = {0.f, 0.f, 0.f, 0.f};
    float wsum = 0.f;
    int i = grp;
    int pp = start + grp*8;
    int4 sv = *(const int4*)&srcsort1[pp];
    bool v0 = i      < cnt, v1 = i + 8  < cnt,
         v2 = i + 16 < cnt, v3 = i + 24 < cnt;
    int s0 = v0 ? sv.x : 0;
    int s1 = v1 ? sv.y : 0;
    int s2 = v2 ? sv.z : 0;
    int s3 = v3 ? sv.w : 0;
    for (;;) {
        float lg0 = esb[s0], lg1 = esb[s1], lg2 = esb[s2], lg3 = esb[s3];
        f4 h0 = *(const f4*)&htb[(size_t)s0*32 + c*4];
        f4 h1 = *(const f4*)&htb[(size_t)s1*32 + c*4];
        f4 h2 = *(const f4*)&htb[(size_t)s2*32 + c*4];
        f4 h3 = *(const f4*)&htb[(size_t)s3*32 + c*4];
        int ni = i + 32;
        bool nv0 = false, nv1 = false, nv2 = false, nv3 = false;
        int t0 = 0, t1 = 0, t2 = 0, t3 = 0;
        if (ni < cnt) {                    // wave-uniform: skip prefetch on final iter
            int4 nsv = *(const int4*)&srcsort1[pp + 4];
            nv0 = true;            nv1 = ni + 8  < cnt;
            nv2 = ni + 16 < cnt;   nv3 = ni + 24 < cnt;
            t0 =       nsv.x;
            t1 = nv1 ? nsv.y : 0;
            t2 = nv2 ? nsv.z : 0;
            t3 = nv3 ? nsv.w : 0;
        }
        lg0 += edv; lg1 += edv; lg2 += edv; lg3 += edv;
        lg0 = lg0 > 0.f ? lg0 : NEG * lg0;
        lg1 = lg1 > 0.f ? lg1 : NEG * lg1;
        lg2 = lg2 > 0.f ? lg2 : NEG * lg2;
        lg3 = lg3 > 0.f ? lg3 : NEG * lg3;
        float w0 = v0 ? __expf(lg0) : 0.f;
        float w1 = v1 ? __expf(lg1) : 0.f;
        float w2 = v2 ? __expf(lg2) : 0.f;
        float w3 = v3 ? __expf(lg3) : 0.f;
        accv += w0 * h0;                   // f4 * scalar -> v_pk_fma_f32 pairs
        accv += w1 * h1;
        accv += w2 * h2;
        accv += w3 * h3;
        wsum += (w0 + w1) + (w2 + w3);
        i = ni; pp += 4;
        s0 = t0; s1 = t1; s2 = t2; s3 = t3;
        v0 = nv0; v1 = nv1; v2 = nv2; v3 = nv3;
        if (i >= cnt) break;
    }
    float ax = accv.x, ay = accv.y, az = accv.z, aw = accv.w;
    ax += __shfl_xor(ax, 8); ax += __shfl_xor(ax, 16); ax += __shfl_xor(ax, 32);
    ay += __shfl_xor(ay, 8); ay += __shfl_xor(ay, 16); ay += __shfl_xor(ay, 32);
    az += __shfl_xor(az, 8); az += __shfl_xor(az, 16); az += __shfl_xor(az, 32);
    aw += __shfl_xor(aw, 8); aw += __shfl_xor(aw, 16); aw += __shfl_xor(aw, 32);
    wsum += __shfl_xor(wsum, 8); wsum += __shfl_xor(wsum, 16); wsum += __shfl_xor(wsum, 32);
    if (grp == 0) {
        float inv = cnt > 0 ? 1.f / wsum : 0.f;
        float4 bb = *(const float4*)&b2[c*4];
        float4 o;
        o.x = ax*inv + bb.x; o.y = ay*inv + bb.y;
        o.z = az*inv + bb.z; o.w = aw*inv + bb.w;
        *(float4*)&outp[((size_t)(b*ND1 + d))*32 + c*4] = o;
    }
}

extern "C" void kernel_launch(void* const* d_in, const int* in_sizes, int n_in,
                              void* d_out, int out_size, void* d_ws, size_t ws_size,
                              hipStream_t stream) {
    const float* x        = (const float*)d_in[0];
    const int*   n_id0    = (const int*)d_in[1];
    const int*   res0     = (const int*)d_in[2];
    const int*   esrc0    = (const int*)d_in[3];
    const int*   edst0    = (const int*)d_in[4];
    const int*   res1     = (const int*)d_in[5];
    const int*   esrc1    = (const int*)d_in[6];
    const int*   edst1    = (const int*)d_in[7];
    const float* W1       = (const float*)d_in[8];
    const float* a_src1   = (const float*)d_in[9];
    const float* a_dst1   = (const float*)d_in[10];
    const float* b1       = (const float*)d_in[11];
    const float* W2       = (const float*)d_in[12];
    const float* a_src2   = (const float*)d_in[13];
    const float* a_dst2   = (const float*)d_in[14];
    const float* b2       = (const float*)d_in[15];
    float* outp = (float*)d_out;

    char* base = (char*)d_ws;
    unsigned short* ht1b = (unsigned short*)base;            // 120000*64*2  = 15,360,000 B
    float* es1  = (float*)(base + 15360000);                 // 960,000 f
    float* ed1  = es1 + 960000;                              // 960,000 f
    float* ht2  = ed1 + 960000;                              // 1,920,000 f
    float* es2  = ht2 + 1920000;                             // 60,000 f
    float* ed2  = es2 + 60000;                               // 60,000 f
    // cur0|cur1 contiguous so one memsetAsync zeroes both
    int* cur0     = (int*)(ed2 + 60000);                     // 15000
    int* cur1     = cur0 + ND0;                              // 7500
    int* srcsort0 = cur1 + ND1;                              // 15000*64 = 960,000
    int* srcsort1 = srcsort0 + ND0*CAP;                      // 7500*64  = 480,000
    // total ~37 MB

    hipMemsetAsync(cur0, 0, (ND0 + ND1) * sizeof(int), stream);
    kA_gemm_scat<<<SBI*4 + (GEMB - SBI*3), 256, 0, stream>>>(x, n_id0, W1, a_src1, a_dst1,
                                                ht1b, es1, ed1,
                                                esrc0, edst0, esrc1, edst1,
                                                cur0, cur1, srcsort0, srcsort1);
    k3_agg1_node2<<<NB*(ND0/4), 256, 0, stream>>>(srcsort0, cur0, res0, es1, ed1, ht1b, b1,
                                                  W2, a_src2, a_dst2, ht2, es2, ed2);
    k7_agg2<<<7504, 256, 0, stream>>>(srcsort1, cur1, res1, es2, ed2, ht2, b2, outp);
}

// Round 11
// 183.243 us; speedup vs baseline: 1.0417x; 1.0417x over previous
//
#include <hip/hip_runtime.h>

#define NB 4
#define NT 40000
#define NS0 30000
#define ND0 15000
#define NE0 360000
#define ND1 7500
#define NE1 180000
#define NEG 0.2f

#define CAP 64                            // bucket capacity per dst (avg deg 24)
#define K1B ((NB*NS0)/64)                 // 1875 GEMM blocks
#define SB8 ((NE0 + NE1 + 2047)/2048)     // 264 scatter blocks (8 edges/thread)

// transposed bucket slot: logical pos p -> physical (p&7)*8 + (p>>3).
// Lane-group grp's 4 edges for iteration k (logical grp+32k+{0,8,16,24})
// land at physical grp*8 + 4k + {0,1,2,3}  -> ONE int4 load per iteration.
#define BKT(p) ((((p) & 7) << 3) | ((p) >> 3))

typedef __attribute__((ext_vector_type(8))) short bf8;
typedef __attribute__((ext_vector_type(4))) float f4;
typedef __attribute__((ext_vector_type(2))) float f2;

__device__ __forceinline__ unsigned short f2bf(float f) {
    unsigned u = __float_as_uint(f);
    u += 0x7FFF + ((u >> 16) & 1);          // round-to-nearest-even
    return (unsigned short)(u >> 16);
}
// unpack a packed bf16 pair (one uint) to 2 floats -> feeds v_pk_fma_f32
__device__ __forceinline__ f2 upk(unsigned u) {
    f2 r;
    r.x = __uint_as_float(u << 16);
    r.y = __uint_as_float(u & 0xFFFF0000u);
    return r;
}

// -------- fused: layer-1 MFMA GEMM + bucket scatter (CSR without scan) -----
// R7 structure (measured best: 184.1 total). One change: x-gather issued
// EARLY (n_id0 lookup + 4 row loads), consumed after W1 staging — the
// staging's independent VALU/LDS work hides the dependent-load chain
// (T14 issue-early/consume-late).
__global__ __launch_bounds__(256) void kA_gemm_scat(
        const float* __restrict__ x, const int* __restrict__ n_id0,
        const float* __restrict__ W1, const float* __restrict__ a_src,
        const float* __restrict__ a_dst,
        unsigned short* __restrict__ ht1b, float* __restrict__ es1, float* __restrict__ ed1,
        const int* __restrict__ esrc0, const int* __restrict__ edst0,
        const int* __restrict__ esrc1, const int* __restrict__ edst1,
        int* __restrict__ cur0, int* __restrict__ cur1,
        int* __restrict__ srcsort0, int* __restrict__ srcsort1) {
    __shared__ unsigned short xtb[64*72];
    __shared__ unsigned short wtb[64*72];
    __shared__ float asl[64], adl[64];
    if (blockIdx.x >= K1B) {                 // ---- scatter part (tail) ----
        int base = (blockIdx.x - K1B) * 2048 + threadIdx.x;
        #pragma unroll
        for (int p = 0; p < 8; ++p) {
            int t = base + p * 256;
            if (t < NE0) {
                int d = edst0[t];
                int pos = atomicAdd(&cur0[d], 1);
                if (pos < CAP) srcsort0[d*CAP + BKT(pos)] = esrc0[t];
            } else if (t < NE0 + NE1) {
                int e = t - NE0;
                int d = edst1[e];
                int pos = atomicAdd(&cur1[d], 1);
                if (pos < CAP) srcsort1[d*CAP + BKT(pos)] = esrc1[e];
            }
        }
        return;
    }
    // ---- GEMM part ----
    int bid = blockIdx.x;
    int t = threadIdx.x;
    // (1) issue the scattered x gather FIRST: dependent chain
    //     n_id0[ns] -> 4 x float4 row loads. Uses come after W1 staging.
    int r   = t >> 2;                     // 4 consecutive lanes share one row
    int sub = t & 3;                      // (16 cache lines/inst, not 64)
    int row_s = bid * 64 + r;
    int bs = row_s / NS0;
    int ns = row_s - bs * NS0;
    const float* xrow = x + ((size_t)(bs * NT + n_id0[ns])) * 64;
    float4 xv0 = *(const float4*)&xrow[(sub +  0) * 4];
    float4 xv1 = *(const float4*)&xrow[(sub +  4) * 4];
    float4 xv2 = *(const float4*)&xrow[(sub +  8) * 4];
    float4 xv3 = *(const float4*)&xrow[(sub + 12) * 4];
    // (2) W1 staging — independent work that overlaps the gather latency
    {
        int k = t >> 2, nb = (t & 3) * 16;
        const float* wrow = &W1[k*64 + nb];
        #pragma unroll
        for (int j = 0; j < 16; j += 4) {
            float4 v = *(const float4*)&wrow[j];
            wtb[(nb+j+0)*72 + k] = f2bf(v.x);
            wtb[(nb+j+1)*72 + k] = f2bf(v.y);
            wtb[(nb+j+2)*72 + k] = f2bf(v.z);
            wtb[(nb+j+3)*72 + k] = f2bf(v.w);
        }
    }
    if (t < 64) { asl[t] = a_src[t]; adl[t] = a_dst[t]; }
    // (3) consume the gather: convert + LDS store
    {
        ushort4 u;
        u.x = f2bf(xv0.x); u.y = f2bf(xv0.y); u.z = f2bf(xv0.z); u.w = f2bf(xv0.w);
        *(ushort4*)&xtb[r*72 + (sub +  0) * 4] = u;
        u.x = f2bf(xv1.x); u.y = f2bf(xv1.y); u.z = f2bf(xv1.z); u.w = f2bf(xv1.w);
        *(ushort4*)&xtb[r*72 + (sub +  4) * 4] = u;
        u.x = f2bf(xv2.x); u.y = f2bf(xv2.y); u.z = f2bf(xv2.z); u.w = f2bf(xv2.w);
        *(ushort4*)&xtb[r*72 + (sub +  8) * 4] = u;
        u.x = f2bf(xv3.x); u.y = f2bf(xv3.y); u.z = f2bf(xv3.z); u.w = f2bf(xv3.w);
        *(ushort4*)&xtb[r*72 + (sub + 12) * 4] = u;
    }
    __syncthreads();
    int w = t >> 6, lane = t & 63, quad = lane >> 4, cl = lane & 15;
    int arow = 16*w + cl;
    bf8 a0 = *(const bf8*)&xtb[arow*72 + quad*8];        // A[m=cl][k=quad*8+j]
    bf8 a1 = *(const bf8*)&xtb[arow*72 + 32 + quad*8];   // k+32
    f4 acc[4];
    #pragma unroll
    for (int sub2 = 0; sub2 < 4; ++sub2) {
        int n = sub2*16 + cl;
        bf8 b0 = *(const bf8*)&wtb[n*72 + quad*8];       // B[k][n=cl]
        bf8 b1v = *(const bf8*)&wtb[n*72 + 32 + quad*8];
        f4 c = {0.f, 0.f, 0.f, 0.f};
        c = __builtin_amdgcn_mfma_f32_16x16x32_bf16(a0, b0, c, 0, 0, 0);
        c = __builtin_amdgcn_mfma_f32_16x16x32_bf16(a1, b1v, c, 0, 0, 0);
        acc[sub2] = c;
    }
    // ---- LDS bounce: C-tile -> xtb (reuse) -> coalesced global ----
    __syncthreads();                       // all xtb/wtb LDS reads complete
    unsigned short* ob = xtb;              // 64 rows x 64 ushort (8 KB)
    #pragma unroll
    for (int sub2 = 0; sub2 < 4; ++sub2)
        #pragma unroll
        for (int rr = 0; rr < 4; ++rr)
            ob[(16*w + 4*quad + rr)*64 + sub2*16 + cl] = f2bf(acc[sub2][rr]);
    // es/ed epilogue (registers + scalar stores)
    int rbase = bid*64 + 16*w + quad*4;
    #pragma unroll
    for (int rr = 0; rr < 4; ++rr) {
        #pragma unroll
        for (int sub2 = 0; sub2 < 4; ++sub2) {
            int col = sub2*16 + cl;
            float ps = acc[sub2][rr] * asl[col];
            float pd = acc[sub2][rr] * adl[col];
            ps += __shfl_xor(ps, 1); ps += __shfl_xor(ps, 2); ps += __shfl_xor(ps, 4);
            pd += __shfl_xor(pd, 1); pd += __shfl_xor(pd, 2); pd += __shfl_xor(pd, 4);
            if ((cl & 7) == 0) {
                int h = sub2*2 + (cl >> 3);
                es1[(rbase + rr)*8 + h] = ps;
                ed1[(rbase + rr)*8 + h] = pd;
            }
        }
    }
    __syncthreads();                       // ob fully written
    {
        int row = t >> 3;                  // 0..31
        int c8  = t & 7;                   // 16-B chunk -> superbank = c8 (conflict-free)
        #pragma unroll
        for (int rep = 0; rep < 2; ++rep) {
            int rr2 = row + rep*32;
            uint4 v = *(const uint4*)&ob[rr2*64 + c8*8];
            *(uint4*)&ht1b[((size_t)(bid*64 + rr2))*64 + c8*8] = v;   // 1024 B/wave-inst
        }
    }
}

// -------- fused: layer-1 aggregation + layer-2 node transform --------------
// (unchanged from R7: 256-thread, 4 dst/block, XCD-pinned, int4 bucket loads,
// pk_fma accumulation, DS-lean epilogue)
__global__ __launch_bounds__(256) void k3_agg1_node2(
        const int* __restrict__ srcsort0, const int* __restrict__ cur0,
        const int* __restrict__ res0,
        const float* __restrict__ es1, const float* __restrict__ ed1,
        const unsigned short* __restrict__ ht1b, const float* __restrict__ b1,
        const float* __restrict__ W2, const float* __restrict__ a_src2,
        const float* __restrict__ a_dst2,
        float* __restrict__ ht2, float* __restrict__ es2, float* __restrict__ ed2) {
    __shared__ float W2t[32][68];          // W2t[c2][k] = W2[k][c2]
    __shared__ float as2[32], ad2[32];
    __shared__ float b1l[64];
    __shared__ float hsh[4][64];           // per-wave h(d)
    int t = threadIdx.x;
    {   // coalesced W2 read (8 KB) + transposed LDS write
        float4 v0 = *(const float4*)&W2[t*8];
        float4 v1 = *(const float4*)&W2[t*8 + 4];
        int k = t >> 2, c = (t & 3) * 8;
        W2t[c+0][k] = v0.x; W2t[c+1][k] = v0.y; W2t[c+2][k] = v0.z; W2t[c+3][k] = v0.w;
        W2t[c+4][k] = v1.x; W2t[c+5][k] = v1.y; W2t[c+6][k] = v1.z; W2t[c+7][k] = v1.w;
    }
    if (t < 32) { as2[t] = a_src2[t]; ad2[t] = a_dst2[t]; }
    if (t < 64) b1l[t] = b1[t];
    __syncthreads();                       // only barrier in the kernel
    int xcd = blockIdx.x & 7;
    int b = xcd >> 1;                      // batch pinned to XCD pair
    int chunk = (blockIdx.x >> 3) * 2 + (xcd & 1);   // 0..3749 (bijective)
    int wv = t >> 6;
    int d = chunk * 4 + wv;
    int lane = t & 63;
    int grp = lane >> 3;                   // edge slot 0..7
    int c = lane & 7;                      // head index; channels 8c..8c+7
    int dn = res0[d];
    float edv = ed1[(b*NS0 + dn)*8 + c];
    int start = d * CAP;
    int cnt = min(cur0[d], CAP);
    const float* esb = es1 + (size_t)b*NS0*8;
    const unsigned short* htb = ht1b + (size_t)b*NS0*64;
    f2 a01 = {0.f, 0.f}, a23 = {0.f, 0.f}, a45 = {0.f, 0.f}, a67 = {0.f, 0.f};
    float wsum = 0.f;
    int i = grp;
    int pp = start + grp*8;                // physical int4 slot for iteration 0
    int4 sv = *(const int4*)&srcsort0[pp];
    bool v0 = i      < cnt, v1 = i + 8  < cnt,
         v2 = i + 16 < cnt, v3 = i + 24 < cnt;
    int s0 = v0 ? sv.x : 0;
    int s1 = v1 ? sv.y : 0;
    int s2 = v2 ? sv.z : 0;
    int s3 = v3 ? sv.w : 0;
    for (;;) {
        float e0 = esb[s0*8 + c], e1 = esb[s1*8 + c];
        float e2 = esb[s2*8 + c], e3 = esb[s3*8 + c];
        uint4 h0 = *(const uint4*)&htb[(size_t)s0*64 + c*8];
        uint4 h1 = *(const uint4*)&htb[(size_t)s1*64 + c*8];
        uint4 h2 = *(const uint4*)&htb[(size_t)s2*64 + c*8];
        uint4 h3 = *(const uint4*)&htb[(size_t)s3*64 + c*8];
        int ni = i + 32;
        bool nv0 = false, nv1 = false, nv2 = false, nv3 = false;
        int t0 = 0, t1 = 0, t2 = 0, t3 = 0;
        if (ni < cnt) {                    // wave-uniform: skip prefetch on final iter
            int4 nsv = *(const int4*)&srcsort0[pp + 4];
            nv0 = true;            nv1 = ni + 8  < cnt;
            nv2 = ni + 16 < cnt;   nv3 = ni + 24 < cnt;
            t0 =       nsv.x;
            t1 = nv1 ? nsv.y : 0;
            t2 = nv2 ? nsv.z : 0;
            t3 = nv3 ? nsv.w : 0;
        }
        e0 += edv; e1 += edv; e2 += edv; e3 += edv;
        e0 = e0 > 0.f ? e0 : NEG * e0;
        e1 = e1 > 0.f ? e1 : NEG * e1;
        e2 = e2 > 0.f ? e2 : NEG * e2;
        e3 = e3 > 0.f ? e3 : NEG * e3;
        float w0 = v0 ? __expf(e0) : 0.f;
        float w1 = v1 ? __expf(e1) : 0.f;
        float w2 = v2 ? __expf(e2) : 0.f;
        float w3 = v3 ? __expf(e3) : 0.f;
        a01 += w0 * upk(h0.x); a23 += w0 * upk(h0.y);
        a45 += w0 * upk(h0.z); a67 += w0 * upk(h0.w);
        a01 += w1 * upk(h1.x); a23 += w1 * upk(h1.y);
        a45 += w1 * upk(h1.z); a67 += w1 * upk(h1.w);
        a01 += w2 * upk(h2.x); a23 += w2 * upk(h2.y);
        a45 += w2 * upk(h2.z); a67 += w2 * upk(h2.w);
        a01 += w3 * upk(h3.x); a23 += w3 * upk(h3.y);
        a45 += w3 * upk(h3.z); a67 += w3 * upk(h3.w);
        wsum += (w0 + w1) + (w2 + w3);
        i = ni; pp += 4;
        s0 = t0; s1 = t1; s2 = t2; s3 = t3;
        v0 = nv0; v1 = nv1; v2 = nv2; v3 = nv3;
        if (i >= cnt) break;
    }
    float acc[8] = {a01.x, a01.y, a23.x, a23.y, a45.x, a45.y, a67.x, a67.y};
    // ---- butterfly reduce-scatter over the 8 edge-slot groups ----
    int g0 = grp & 1, g1 = (grp >> 1) & 1, g2 = grp >> 2;
    float n0, n1, n2, n3;
    {
        float s, r;
        s = g0 ? acc[0] : acc[1]; r = __shfl_xor(s, 8);  n0 = (g0 ? acc[1] : acc[0]) + r;
        s = g0 ? acc[2] : acc[3]; r = __shfl_xor(s, 8);  n1 = (g0 ? acc[3] : acc[2]) + r;
        s = g0 ? acc[4] : acc[5]; r = __shfl_xor(s, 8);  n2 = (g0 ? acc[5] : acc[4]) + r;
        s = g0 ? acc[6] : acc[7]; r = __shfl_xor(s, 8);  n3 = (g0 ? acc[7] : acc[6]) + r;
    }
    float m0, m1;
    {
        float s, r;
        s = g1 ? n0 : n1; r = __shfl_xor(s, 16); m0 = (g1 ? n1 : n0) + r;
        s = g1 ? n2 : n3; r = __shfl_xor(s, 16); m1 = (g1 ? n3 : n2) + r;
    }
    float fin;
    {
        float s = g2 ? m0 : m1; float r = __shfl_xor(s, 32); fin = (g2 ? m1 : m0) + r;
    }
    wsum += __shfl_xor(wsum, 8); wsum += __shfl_xor(wsum, 16); wsum += __shfl_xor(wsum, 32);
    float inv = cnt > 0 ? 1.f / wsum : 0.f;
    float o = fin * inv + b1l[(c << 3) | grp];
    o = o > 0.f ? o : __expf(o) - 1.f;     // ELU: 1 exp/lane, all 64 lanes
    hsh[wv][(c << 3) | grp] = o;
    // hsh[wv] written+read by the SAME wave -> lgkmcnt ordering suffices.
    // ---- layer-2 node transform: out[c2] = sum_k h[k] * W2t[c2][k] ----
    int c2 = lane & 31, half = lane >> 5;
    const float4* hp = (const float4*)&hsh[wv][half * 32];
    const float4* wp = (const float4*)&W2t[c2][half * 32];
    float acc2 = 0.f;
    #pragma unroll
    for (int q = 0; q < 8; ++q) {
        float4 hv = hp[q];
        float4 w4 = wp[q];
        acc2 = fmaf(hv.x, w4.x, acc2); acc2 = fmaf(hv.y, w4.y, acc2);
        acc2 = fmaf(hv.z, w4.z, acc2); acc2 = fmaf(hv.w, w4.w, acc2);
    }
    acc2 += __shfl_xor(acc2, 32);
    float ps = acc2 * as2[c2];
    float pd = acc2 * ad2[c2];
    ps += __shfl_xor(ps, 1); ps += __shfl_xor(ps, 2); ps += __shfl_xor(ps, 4);
    ps += __shfl_xor(ps, 8); ps += __shfl_xor(ps, 16);
    pd += __shfl_xor(pd, 1); pd += __shfl_xor(pd, 2); pd += __shfl_xor(pd, 4);
    pd += __shfl_xor(pd, 8); pd += __shfl_xor(pd, 16);
    int row = b*ND0 + d;
    if (half == 0) ht2[(size_t)row*32 + c2] = acc2;   // coalesced 128 B
    if (lane == 0) { es2[row] = ps; ed2[row] = pd; }
}

// ---------------- layer 2 per-dst aggregation ------------------------------
// (unchanged from R7: 256-thread, pinned, grid 7504 + guard, int4 loads)
__global__ __launch_bounds__(256) void k7_agg2(
        const int* __restrict__ srcsort1, const int* __restrict__ cur1,
        const int* __restrict__ res1,
        const float* __restrict__ es2, const float* __restrict__ ed2,
        const float* __restrict__ ht2, const float* __restrict__ b2,
        float* __restrict__ outp) {
    int xcd = blockIdx.x & 7;
    int b = xcd >> 1;
    int chunk = (blockIdx.x >> 3) * 2 + (xcd & 1);
    if (chunk >= ND1/4) return;            // pad blocks (grid 7504)
    int d = chunk * 4 + (threadIdx.x >> 6);
    int lane = threadIdx.x & 63;
    int grp = lane >> 3;                   // edge slot 0..7
    int c = lane & 7;                      // channel quad: channels 4c..4c+3
    int dn = res1[d];
    float edv = ed2[b*ND0 + dn];
    int start = d * CAP;
    int cnt = min(cur1[d], CAP);
    const float* esb = es2 + (size_t)b*ND0;
    const float* htb = ht2 + (size_t)b*ND0*32;
    f4 accv = {0.f, 0.f, 0.f, 0.f};
    float wsum = 0.f;
    int i = grp;
    int pp = start + grp*8;
    int4 sv = *(const int4*)&srcsort1[pp];
    bool v0 = i      < cnt, v1 = i + 8  < cnt,
         v2 = i + 16 < cnt, v3 = i + 24 < cnt;
    int s0 = v0 ? sv.x : 0;
    int s1 = v1 ? sv.y : 0;
    int s2 = v2 ? sv.z : 0;
    int s3 = v3 ? sv.w : 0;
    for (;;) {
        float lg0 = esb[s0], lg1 = esb[s1], lg2 = esb[s2], lg3 = esb[s3];
        f4 h0 = *(const f4*)&htb[(size_t)s0*32 + c*4];
        f4 h1 = *(const f4*)&htb[(size_t)s1*32 + c*4];
        f4 h2 = *(const f4*)&htb[(size_t)s2*32 + c*4];
        f4 h3 = *(const f4*)&htb[(size_t)s3*32 + c*4];
        int ni = i + 32;
        bool nv0 = false, nv1 = false, nv2 = false, nv3 = false;
        int t0 = 0, t1 = 0, t2 = 0, t3 = 0;
        if (ni < cnt) {                    // wave-uniform: skip prefetch on final iter
            int4 nsv = *(const int4*)&srcsort1[pp + 4];
            nv0 = true;            nv1 = ni + 8  < cnt;
            nv2 = ni + 16 < cnt;   nv3 = ni + 24 < cnt;
            t0 =       nsv.x;
            t1 = nv1 ? nsv.y : 0;
            t2 = nv2 ? nsv.z : 0;
            t3 = nv3 ? nsv.w : 0;
        }
        lg0 += edv; lg1 += edv; lg2 += edv; lg3 += edv;
        lg0 = lg0 > 0.f ? lg0 : NEG * lg0;
        lg1 = lg1 > 0.f ? lg1 : NEG * lg1;
        lg2 = lg2 > 0.f ? lg2 : NEG * lg2;
        lg3 = lg3 > 0.f ? lg3 : NEG * lg3;
        float w0 = v0 ? __expf(lg0) : 0.f;
        float w1 = v1 ? __expf(lg1) : 0.f;
        float w2 = v2 ? __expf(lg2) : 0.f;
        float w3 = v3 ? __expf(lg3) : 0.f;
        accv += w0 * h0;                   // f4 * scalar -> v_pk_fma_f32 pairs
        accv += w1 * h1;
        accv += w2 * h2;
        accv += w3 * h3;
        wsum += (w0 + w1) + (w2 + w3);
        i = ni; pp += 4;
        s0 = t0; s1 = t1; s2 = t2; s3 = t3;
        v0 = nv0; v1 = nv1; v2 = nv2; v3 = nv3;
        if (i >= cnt) break;
    }
    float ax = accv.x, ay = accv.y, az = accv.z, aw = accv.w;
    ax += __shfl_xor(ax, 8); ax += __shfl_xor(ax, 16); ax += __shfl_xor(ax, 32);
    ay += __shfl_xor(ay, 8); ay += __shfl_xor(ay, 16); ay += __shfl_xor(ay, 32);
    az += __shfl_xor(az, 8); az += __shfl_xor(az, 16); az += __shfl_xor(az, 32);
    aw += __shfl_xor(aw, 8); aw += __shfl_xor(aw, 16); aw += __shfl_xor(aw, 32);
    wsum += __shfl_xor(wsum, 8); wsum += __shfl_xor(wsum, 16); wsum += __shfl_xor(wsum, 32);
    if (grp == 0) {
        float inv = cnt > 0 ? 1.f / wsum : 0.f;
        float4 bb = *(const float4*)&b2[c*4];
        float4 o;
        o.x = ax*inv + bb.x; o.y = ay*inv + bb.y;
        o.z = az*inv + bb.z; o.w = aw*inv + bb.w;
        *(float4*)&outp[((size_t)(b*ND1 + d))*32 + c*4] = o;
    }
}

extern "C" void kernel_launch(void* const* d_in, const int* in_sizes, int n_in,
                              void* d_out, int out_size, void* d_ws, size_t ws_size,
                              hipStream_t stream) {
    const float* x        = (const float*)d_in[0];
    const int*   n_id0    = (const int*)d_in[1];
    const int*   res0     = (const int*)d_in[2];
    const int*   esrc0    = (const int*)d_in[3];
    const int*   edst0    = (const int*)d_in[4];
    const int*   res1     = (const int*)d_in[5];
    const int*   esrc1    = (const int*)d_in[6];
    const int*   edst1    = (const int*)d_in[7];
    const float* W1       = (const float*)d_in[8];
    const float* a_src1   = (const float*)d_in[9];
    const float* a_dst1   = (const float*)d_in[10];
    const float* b1       = (const float*)d_in[11];
    const float* W2       = (const float*)d_in[12];
    const float* a_src2   = (const float*)d_in[13];
    const float* a_dst2   = (const float*)d_in[14];
    const float* b2       = (const float*)d_in[15];
    float* outp = (float*)d_out;

    char* base = (char*)d_ws;
    unsigned short* ht1b = (unsigned short*)base;            // 120000*64*2  = 15,360,000 B
    float* es1  = (float*)(base + 15360000);                 // 960,000 f
    float* ed1  = es1 + 960000;                              // 960,000 f
    float* ht2  = ed1 + 960000;                              // 1,920,000 f
    float* es2  = ht2 + 1920000;                             // 60,000 f
    float* ed2  = es2 + 60000;                               // 60,000 f
    // cur0|cur1 contiguous so one memsetAsync zeroes both
    int* cur0     = (int*)(ed2 + 60000);                     // 15000
    int* cur1     = cur0 + ND0;                              // 7500
    int* srcsort0 = cur1 + ND1;                              // 15000*64 = 960,000
    int* srcsort1 = srcsort0 + ND0*CAP;                      // 7500*64  = 480,000
    // total ~37 MB

    hipMemsetAsync(cur0, 0, (ND0 + ND1) * sizeof(int), stream);
    kA_gemm_scat<<<K1B + SB8, 256, 0, stream>>>(x, n_id0, W1, a_src1, a_dst1,
                                                ht1b, es1, ed1,
                                                esrc0, edst0, esrc1, edst1,
                                                cur0, cur1, srcsort0, srcsort1);
    k3_agg1_node2<<<NB*(ND0/4), 256, 0, stream>>>(srcsort0, cur0, res0, es1, ed1, ht1b, b1,
                                                  W2, a_src2, a_dst2, ht2, es2, ed2);
    k7_agg2<<<7504, 256, 0, stream>>>(srcsort1, cur1, res1, es2, ed2, ht2, b2, outp);
}